// Round 3
// baseline (776.942 us; speedup 1.0000x reference)
//
#include <hip/hip_runtime.h>
#include <math.h>

// Problem constants
#define Bn  16
#define ICn 16
#define Dn  16
#define Hn  128
#define Wn  128
#define OCn 32
#define DPn 14
#define HPn 126
#define WPn 126

typedef _Float16 half_t;
typedef __attribute__((ext_vector_type(4)))  _Float16 half4;
typedef __attribute__((ext_vector_type(8)))  _Float16 half8;
typedef __attribute__((ext_vector_type(16))) float    float16v;

// Tile config: wg = 4 waves; each wave: 32 pixels (2 rows x 16 cols) x 32 oc.
#define TH 8
#define TW 16
#define SR 10            // TH + 2 halo
#define SC 18            // TW + 2 halo
#define COL_B 40         // 20 halves per col (pad 16->20): 40B stride, 2-way banks = free
#define ROW_B (SC*COL_B) // 720 B
#define SLOT_BYTES (SR*ROW_B)  // 7200 B
#define NSLOT 4
#define EP_PAD 33
#define NCHUNK (SR*SC*2) // 360 16B-chunks per plane slot

// ---------------------------------------------------------------------------
// Pre-pass 1: weights -> B-fragment order for mfma_f32_32x32x16_f16
//   lane l holds B[n=l&31][k=(l>>5)*8+j], j=0..7 (n=oc, k=ic); wB[tap][lane][j]
// ---------------------------------------------------------------------------
__global__ void pack_w_kernel(const float* __restrict__ w, half_t* __restrict__ wB) {
    int i = blockIdx.x * 256 + threadIdx.x;      // 27*64*8 = 13824
    if (i >= 27 * 64 * 8) return;
    int tap = i >> 9;
    int l   = (i >> 3) & 63;
    int j   = i & 7;
    int oc  = l & 31;
    int ic  = ((l >> 5) << 3) + j;
    wB[i] = (half_t)w[(oc * ICn + ic) * 27 + tap];
}

// ---------------------------------------------------------------------------
// Pre-pass 2: x f32 NCDHW -> f16 channels-last [b][d][h][w][ic].
// Thread t owns w=t for one (b,d,h) row: 16 coalesced ic-loads (per-ic, 128
// lanes contiguous), pack pairs in registers, one 32B contiguous store.
// ---------------------------------------------------------------------------
__global__ void cvt_kernel(const float* __restrict__ x, half_t* __restrict__ y) {
    const int t  = threadIdx.x & 127;
    const int hs = threadIdx.x >> 7;
    const int h  = blockIdx.x * 2 + hs;          // gridDim.x = 64
    const int d  = blockIdx.y;
    const int b  = blockIdx.z;

    const float* xp = x + ((size_t)(b * ICn) * Dn + d) * Hn * Wn + (size_t)h * Wn + t;
    const size_t icStride = (size_t)Dn * Hn * Wn;

    uint r[8];
#pragma unroll
    for (int icp = 0; icp < 8; ++icp) {
        float v0 = xp[(size_t)(2 * icp) * icStride];
        float v1 = xp[(size_t)(2 * icp + 1) * icStride];
        union { half_t h2[2]; uint u; } pk;
        pk.h2[0] = (half_t)v0; pk.h2[1] = (half_t)v1;
        r[icp] = pk.u;
    }
    uint4* dst = (uint4*)(y + ((((size_t)b * Dn + d) * Hn + h) * Wn + t) * ICn);
    dst[0] = *(uint4*)&r[0];
    dst[1] = *(uint4*)&r[4];
}

// ---------------------------------------------------------------------------
// Main: implicit-GEMM conv -> min(d) -> softmax(oc).
// 4-slot LDS ring, ONE barrier per dp, global prefetch overlapped with MFMA.
// ---------------------------------------------------------------------------
__launch_bounds__(256, 3)
__global__ void conv_min_softmax_mfma(const half_t* __restrict__ xt,
                                      const half_t* __restrict__ wB,
                                      const float* __restrict__ bias,
                                      float* __restrict__ out) {
    __shared__ __align__(16) char smem[NSLOT * SLOT_BYTES];   // 28.8 KB; epilogue reuses it

    const int tid    = threadIdx.x;
    const int lane   = tid & 63;
    const int wv     = tid >> 6;
    const int wpbase = blockIdx.x * TW;
    const int hpbase = blockIdx.y * TH;
    const int b      = blockIdx.z;

    const half_t* xb = xt + (size_t)b * Dn * Hn * Wn * ICn;

    // B-fragments for all 27 taps, held in registers (108 VGPRs)
    half8 wf[27];
#pragma unroll
    for (int t = 0; t < 27; ++t)
        wf[t] = *(const half8*)(wB + ((size_t)t * 64 + lane) * 8);

    // staging address helpers: chunk c -> (row=c/36, col=(c%36)>>1, hf=(c%36)&1)
    auto srcAddr = [&](int d, int c) -> const uint4* {
        int row = c / (SC * 2), rem = c % (SC * 2);
        int col = rem >> 1, hf = rem & 1;
        int gr = hpbase + row; if (gr > Hn - 1) gr = Hn - 1;
        int gc = wpbase + col; if (gc > Wn - 1) gc = Wn - 1;
        return (const uint4*)(xb + (((size_t)d * Hn + gr) * Wn + gc) * ICn + hf * 8);
    };
    auto ldsOff = [&](int slot, int c) -> char* {
        int row = c / (SC * 2), rem = c % (SC * 2);
        int col = rem >> 1, hf = rem & 1;
        return smem + slot * SLOT_BYTES + row * ROW_B + col * COL_B + hf * 16;
    };
    auto writeChunk = [&](char* p, uint4 v) {
        ((uint2*)p)[0] = make_uint2(v.x, v.y);   // 8B-aligned LDS writes
        ((uint2*)p)[1] = make_uint2(v.z, v.w);
    };
    auto stageNow = [&](int d, int slot) {
        uint4 v0 = *srcAddr(d, tid);
        writeChunk(ldsOff(slot, tid), v0);
        if (tid < NCHUNK - 256) {
            uint4 v1 = *srcAddr(d, tid + 256);
            writeChunk(ldsOff(slot, tid + 256), v1);
        }
    };

    // A-frag decode: m=lane&31 -> (prow=m>>4, pcol=m&15); h=lane>>5 -> k-half
    const int m    = lane & 31;
    const int h    = lane >> 5;
    const int prow = m >> 4, pcol = m & 15;
    const int albase = (2 * wv + prow) * ROW_B + pcol * COL_B + 16 * h;

    // prologue: planes 0,1,2 -> slots 0,1,2 (plane p lives in slot p&3)
    stageNow(0, 0); stageNow(1, 1); stageNow(2, 2);
    __syncthreads();

    float16v mn;
#pragma unroll
    for (int r = 0; r < 16; ++r) mn[r] = INFINITY;

    for (int dp = 0; dp < DPn; ++dp) {
        const bool st = (dp < DPn - 1);          // plane dp+3 exists (dp+3 <= 15)
        uint4 p0, p1;
        if (st) {                                 // prefetch: loads in flight over MFMAs
            p0 = *srcAddr(dp + 3, tid);
            if (tid < NCHUNK - 256) p1 = *srcAddr(dp + 3, tid + 256);
        }

        float16v acc;
#pragma unroll
        for (int r = 0; r < 16; ++r) acc[r] = 0.0f;

#pragma unroll
        for (int kd = 0; kd < 3; ++kd) {
            const char* ab = smem + ((dp + kd) & 3) * SLOT_BYTES + albase;
#pragma unroll
            for (int kh = 0; kh < 3; ++kh) {
#pragma unroll
                for (int kw = 0; kw < 3; ++kw) {
                    const int off = kh * ROW_B + kw * COL_B;
                    half4 a0 = *(const half4*)(ab + off);
                    half4 a1 = *(const half4*)(ab + off + 8);
                    half8 a = __builtin_shufflevector(a0, a1, 0, 1, 2, 3, 4, 5, 6, 7);
                    acc = __builtin_amdgcn_mfma_f32_32x32x16_f16(a, wf[kd * 9 + kh * 3 + kw], acc, 0, 0, 0);
                }
            }
        }
#pragma unroll
        for (int r = 0; r < 16; ++r) mn[r] = fminf(mn[r], acc[r]);

        if (st) {                                 // write prefetched plane into free slot
            const int slot = (dp + 3) & 3;        // disjoint from (dp..dp+2)&3
            writeChunk(ldsOff(slot, tid), p0);
            if (tid < NCHUNK - 256) writeChunk(ldsOff(slot, tid + 256), p1);
        }
        __syncthreads();                          // ONE barrier per dp
    }

    // epilogue: bias + softmax over oc (32-lane shfl), transpose via LDS (reuse smem)
    const int oc = m;
    const float bv = bias[oc];
    float* ep = (float*)smem;                     // 4*32*33*4 = 16.9 KB <= 28.8 KB

#pragma unroll
    for (int reg = 0; reg < 16; ++reg) {
        float v = mn[reg] + bv;
        float mx = v;
#pragma unroll
        for (int off = 1; off < 32; off <<= 1)
            mx = fmaxf(mx, __shfl_xor(mx, off, 64));
        float e = __expf(v - mx);
        float s = e;
#pragma unroll
        for (int off = 1; off < 32; off <<= 1)
            s += __shfl_xor(s, off, 64);
        float pr = e / s;
        int mc = (reg & 3) + ((reg >> 2) << 3) + 4 * h;   // C/D row (pixel)
        ep[(wv * 32 + mc) * EP_PAD + oc] = pr;
    }
    __syncthreads();

    for (int i = tid; i < 32 * TH * TW; i += 256) {
        int oc2  = i >> 7;
        int rrow = (i >> 4) & 7;
        int col  = i & 15;
        int wvs = rrow >> 1, pr2 = rrow & 1;
        int mc  = pr2 * 16 + col;
        float val = ep[(wvs * 32 + mc) * EP_PAD + oc2];
        int hp = hpbase + rrow, wp = wpbase + col;
        if (hp < HPn && wp < WPn)
            out[((b * OCn + oc2) * HPn + hp) * WPn + wp] = val;
    }
}

extern "C" void kernel_launch(void* const* d_in, const int* in_sizes, int n_in,
                              void* d_out, int out_size, void* d_ws, size_t ws_size,
                              hipStream_t stream) {
    const float* x    = (const float*)d_in[0];
    const float* w    = (const float*)d_in[1];
    const float* bias = (const float*)d_in[2];
    float* out        = (float*)d_out;

    half_t* wB = (half_t*)d_ws;                           // 27.6 KB
    half_t* xt = (half_t*)((char*)d_ws + 32768);          // 134.2 MB f16 channels-last

    {
        int n = 27 * 64 * 8;
        pack_w_kernel<<<(n + 255) / 256, 256, 0, stream>>>(w, wB);
    }
    {
        dim3 grid(Hn / 2, Dn, Bn);                        // 64 x 16 x 16
        cvt_kernel<<<grid, 256, 0, stream>>>(x, xt);
    }
    {
        dim3 grid((WPn + TW - 1) / TW,                    // 8
                  (HPn + TH - 1) / TH,                    // 16
                  Bn);                                    // 16
        conv_min_softmax_mfma<<<grid, 256, 0, stream>>>(xt, wB, bias, out);
    }
}

// Round 4
// 633.801 us; speedup vs baseline: 1.2258x; 1.2258x over previous
//
#include <hip/hip_runtime.h>
#include <math.h>

// Problem constants
#define Bn  16
#define ICn 16
#define Dn  16
#define Hn  128
#define Wn  128
#define OCn 32
#define DPn 14
#define HPn 126
#define WPn 126

typedef _Float16 half_t;
typedef __attribute__((ext_vector_type(4)))  _Float16 half4;
typedef __attribute__((ext_vector_type(8)))  _Float16 half8;
typedef __attribute__((ext_vector_type(16))) float    float16v;

// Tile: wg = 4 waves; each wave 32 pixels (2 rows x 16 cols) x 32 oc.
#define TH 8
#define TW 16
#define SR 10                  // TH + 2 halo
#define SC 18                  // TW + 2 halo
#define COL_B 40               // 20 halves per col (16 ic + pad): 2-way banks = free
#define ROW_B (SC*COL_B)       // 720 B
#define SLOT_BYTES (SR*ROW_B)  // 7200 B
#define EP_PAD 33
#define NTASK (SR*SC*8)        // 1440 ic-pair staging tasks per plane
#define NITER 6                // ceil(NTASK/256)

// ---------------------------------------------------------------------------
// Pre-pass: weights -> B-fragment order for mfma_f32_32x32x16_f16
//   lane l holds B[n=l&31][k=(l>>5)*8+j], j=0..7 (n=oc, k=ic); wB[tap][lane][j]
// ---------------------------------------------------------------------------
__global__ void pack_w_kernel(const float* __restrict__ w, half_t* __restrict__ wB) {
    int i = blockIdx.x * 256 + threadIdx.x;      // 27*64*8 = 13824
    if (i >= 27 * 64 * 8) return;
    int tap = i >> 9;
    int l   = (i >> 3) & 63;
    int j   = i & 7;
    int oc  = l & 31;
    int ic  = ((l >> 5) << 3) + j;
    wB[i] = (half_t)w[(oc * ICn + ic) * 27 + tap];
}

// ---------------------------------------------------------------------------
// Fused implicit-GEMM conv3d -> min(depth) -> softmax(channels).
// f32 NCDHW staged directly (cvt in regs). 4-slot LDS ring, ONE barrier/dp,
// register prefetch of plane dp+3 issued before the 27-MFMA block.
// (256,2): budget 256 unified regs/wave -> no spill (R3's 488MB WRITE was spill)
// ---------------------------------------------------------------------------
__launch_bounds__(256, 2)
__global__ void conv_min_softmax_mfma(const float* __restrict__ x,
                                      const half_t* __restrict__ wB,
                                      const float* __restrict__ bias,
                                      float* __restrict__ out) {
    __shared__ __align__(16) char smem[4 * SLOT_BYTES];   // 28.8 KB

    const int tid    = threadIdx.x;
    const int lane   = tid & 63;
    const int wv     = tid >> 6;
    const int wpbase = blockIdx.x * TW;
    const int hpbase = blockIdx.y * TH;
    const int b      = blockIdx.z;

    const float* xb  = x + (size_t)b * ICn * Dn * Hn * Wn;
    const size_t icS = (size_t)Dn * Hn * Wn;       // element stride between ic

    // B-fragments for all 27 taps in registers (108 regs, AGPR-side of file)
    half8 wf[27];
#pragma unroll
    for (int t = 0; t < 27; ++t)
        wf[t] = *(const half8*)(wB + ((size_t)t * 64 + lane) * 8);

    // --- precompute staging geometry once (dp-invariant): 6 tasks/thread ---
    const float* gsrc[NITER];   // base addr at d=0 for ic=2*icp
    int loff[NITER];            // LDS byte offset within a slot
#pragma unroll
    for (int j = 0; j < NITER; ++j) {
        int c = tid + j * 256;
        int cc = (c < NTASK) ? c : 0;
        int icp = cc / (SR * SC);
        int rem = cc % (SR * SC);
        int row = rem / SC, col = rem % SC;
        int gr = hpbase + row; if (gr > Hn - 1) gr = Hn - 1;   // clamp halo
        int gc = wpbase + col; if (gc > Wn - 1) gc = Wn - 1;
        gsrc[j] = xb + (size_t)(2 * icp) * icS + (size_t)gr * Wn + gc;
        loff[j] = rem * COL_B + icp * 4;
    }
    const bool tail = (tid < NTASK - (NITER - 1) * 256);   // only j=5 is partial

    auto stageLoad = [&](int d, float* v) {
#pragma unroll
        for (int j = 0; j < NITER; ++j) {
            if (j < NITER - 1 || tail) {
                const float* p = gsrc[j] + (size_t)d * (Hn * Wn);
                v[2 * j]     = p[0];
                v[2 * j + 1] = p[icS];
            }
        }
    };
    auto stageWrite = [&](int slot, const float* v) {
        char* sb = smem + slot * SLOT_BYTES;
#pragma unroll
        for (int j = 0; j < NITER; ++j) {
            if (j < NITER - 1 || tail) {
                union { half_t h2[2]; unsigned u; } pk;
                pk.h2[0] = (half_t)v[2 * j];
                pk.h2[1] = (half_t)v[2 * j + 1];
                *(unsigned*)(sb + loff[j]) = pk.u;
            }
        }
    };

    // A-frag decode: m=lane&31 -> (prow=m>>4, pcol=m&15); h=lane>>5 -> k-octet
    const int m    = lane & 31;
    const int h    = lane >> 5;
    const int prow = m >> 4, pcol = m & 15;
    const int albase = (2 * wv + prow) * ROW_B + pcol * COL_B + 16 * h;

    // prologue: planes 0,1,2 -> slots 0,1,2 (plane p lives in slot p&3)
    {
        float v[2 * NITER];
        stageLoad(0, v); stageWrite(0, v);
        stageLoad(1, v); stageWrite(1, v);
        stageLoad(2, v); stageWrite(2, v);
    }
    __syncthreads();

    float16v mn;
#pragma unroll
    for (int r = 0; r < 16; ++r) mn[r] = INFINITY;

    for (int dp = 0; dp < DPn; ++dp) {
        const bool st = (dp < DPn - 1);
        float pv[2 * NITER];
        if (st) stageLoad(dp + 3, pv);     // loads in flight across the MFMAs

        float16v acc;
#pragma unroll
        for (int r = 0; r < 16; ++r) acc[r] = 0.0f;

#pragma unroll
        for (int kd = 0; kd < 3; ++kd) {
            const char* ab = smem + ((dp + kd) & 3) * SLOT_BYTES + albase;
#pragma unroll
            for (int kh = 0; kh < 3; ++kh) {
#pragma unroll
                for (int kw = 0; kw < 3; ++kw) {
                    const int off = kh * ROW_B + kw * COL_B;
                    half4 a0 = *(const half4*)(ab + off);
                    half4 a1 = *(const half4*)(ab + off + 8);
                    half8 a = __builtin_shufflevector(a0, a1, 0, 1, 2, 3, 4, 5, 6, 7);
                    acc = __builtin_amdgcn_mfma_f32_32x32x16_f16(
                        a, wf[kd * 9 + kh * 3 + kw], acc, 0, 0, 0);
                }
            }
        }
#pragma unroll
        for (int r = 0; r < 16; ++r) mn[r] = fminf(mn[r], acc[r]);

        if (st) stageWrite((dp + 3) & 3, pv);  // slot disjoint from (dp+1..dp+3)&3
        __syncthreads();                        // ONE barrier per dp
    }

    // epilogue: bias + softmax over oc (32-lane shfl), transpose via LDS reuse
    const int oc = m;                           // C/D: col(n=oc) = lane&31
    const float bv = bias[oc];
    float* ep = (float*)smem;                   // 16.9 KB <= 28.8 KB

#pragma unroll
    for (int reg = 0; reg < 16; ++reg) {
        float v = mn[reg] + bv;
        float mx = v;
#pragma unroll
        for (int off = 1; off < 32; off <<= 1)
            mx = fmaxf(mx, __shfl_xor(mx, off, 64));
        float e = __expf(v - mx);
        float s = e;
#pragma unroll
        for (int off = 1; off < 32; off <<= 1)
            s += __shfl_xor(s, off, 64);
        float pr = e / s;
        int mc = (reg & 3) + ((reg >> 2) << 3) + 4 * h;    // C/D row (pixel)
        ep[(wv * 32 + mc) * EP_PAD + oc] = pr;
    }
    __syncthreads();

    for (int i = tid; i < 32 * TH * TW; i += 256) {
        int oc2  = i >> 7;
        int rrow = (i >> 4) & 7;
        int col  = i & 15;
        int wvs = rrow >> 1, pr2 = rrow & 1;
        int mc  = pr2 * 16 + col;
        float val = ep[(wvs * 32 + mc) * EP_PAD + oc2];
        int hp = hpbase + rrow, wp = wpbase + col;
        if (hp < HPn && wp < WPn)
            out[((b * OCn + oc2) * HPn + hp) * WPn + wp] = val;
    }
}

extern "C" void kernel_launch(void* const* d_in, const int* in_sizes, int n_in,
                              void* d_out, int out_size, void* d_ws, size_t ws_size,
                              hipStream_t stream) {
    const float* x    = (const float*)d_in[0];
    const float* w    = (const float*)d_in[1];
    const float* bias = (const float*)d_in[2];
    float* out        = (float*)d_out;
    half_t* wB        = (half_t*)d_ws;          // 27.6 KB scratch

    {
        int n = 27 * 64 * 8;
        pack_w_kernel<<<(n + 255) / 256, 256, 0, stream>>>(w, wB);
    }
    {
        dim3 grid((WPn + TW - 1) / TW,          // 8
                  (HPn + TH - 1) / TH,          // 16
                  Bn);                          // 16
        conv_min_softmax_mfma<<<grid, 256, 0, stream>>>(x, wB, bias, out);
    }
}